// Round 9
// baseline (3385.006 us; speedup 1.0000x reference)
//
#include <hip/hip_runtime.h>
#include <hip/hip_bf16.h>
#include <stdint.h>

// RecognitionODEGRU R8 — R6 base (proven correct, 3119us) + verified XCD-local
// fast data path. Counters ALWAYS agent-scope (MALL) — R7 died on workgroup
// atomics + sc0 counter spins. Fast chains (XCC_ID-grouped AND probe-verified):
// activations via plain stores (XCD L2) + asm sc0 loads (L1-bypass, L2-hit).
// Probe failure or non-uniform placement -> chain-uniform R6 MALL fallback.
//
// Shapes: B=512, T=8, D=512, H=512, NSTEPS=4.
// d_out: outs[-1] (512,128) | h (512,512) | c=zeros (512,512), f32.

#define B_ 512
#define T_ 8
#define H_ 512
#define D_ 512

typedef short short8 __attribute__((ext_vector_type(8)));
typedef float f32x4 __attribute__((ext_vector_type(4)));
typedef __hip_bfloat16 bf16;
typedef unsigned long long u64;

__device__ __forceinline__ float sigm(float x){ return 1.f/(1.f+__expf(-x)); }

#define MFMA16(a,b,c) __builtin_amdgcn_mfma_f32_16x16x32_bf16((a),(b),(c),0,0,0)
#define ALD4(p)   __hip_atomic_load((p), __ATOMIC_RELAXED, __HIP_MEMORY_SCOPE_AGENT)
#define AST4(p,v) __hip_atomic_store((p),(v),__ATOMIC_RELAXED,__HIP_MEMORY_SCOPE_AGENT)
#define ALD8(p)   __hip_atomic_load((const u64*)(p), __ATOMIC_RELAXED, __HIP_MEMORY_SCOPE_AGENT)
#define AST8(p,v) __hip_atomic_store((u64*)(p),(v),__ATOMIC_RELAXED,__HIP_MEMORY_SCOPE_AGENT)
#define AADD(p)   __hip_atomic_fetch_add((p),1u,__ATOMIC_RELAXED,__HIP_MEMORY_SCOPE_AGENT)

__device__ __forceinline__ int xcc_id(){
  // HW_REG_XCC_ID = 20, offset 0, width 4 (m09)
  return (int)(__builtin_amdgcn_s_getreg(20 | (3 << 11)) & 7);
}

// Counter spin/publish — agent scope (MALL) in ALL modes (R6-proven).
__device__ __forceinline__ void wait_ge(unsigned* c, unsigned tgt, int* dead){
  if (threadIdx.x == 0){
    if (!*dead){
      int it = 0;
      while (ALD4(c) < tgt){
        __builtin_amdgcn_s_sleep(1);
        if (++it > 50000000){ *dead = 1; break; }  // terminate visibly, no hang
      }
    }
  }
  __syncthreads();
}
__device__ __forceinline__ void publish(unsigned* c){
  __builtin_amdgcn_s_waitcnt(0);   // each wave drains its stores before barrier
  __syncthreads();
  if (threadIdx.x == 0) AADD(c);
}

// ---- SLOW staging (R6-proven): batched 8B agent-scope loads -> LDS ----
template<int CH, int SH>
__device__ __forceinline__ void stageC(bf16* lds, int lstr, const bf16* g, int gstr){
  u64 tmp[CH];
#pragma unroll
  for (int j = 0; j < CH; ++j){
    int idx = j*256 + threadIdx.x;
    tmp[j] = ALD8(g + (size_t)(idx >> SH)*gstr + (size_t)(idx & ((1<<SH)-1))*4);
  }
#pragma unroll
  for (int j = 0; j < CH; ++j){
    int idx = j*256 + threadIdx.x;
    *(u64*)&lds[(idx >> SH)*lstr + (idx & ((1<<SH)-1))*4] = tmp[j];
  }
}
// ---- FAST staging: 16B sc0 loads (bypass L1, hit shared XCD L2) -> LDS ----
template<int NCH, int SH>
__device__ __forceinline__ void stageF(bf16* lds, int lstr, const bf16* g, int gstr){
  short8 tmp[NCH];
  asm volatile("" ::: "memory");          // compiler fence: loads stay after wait
#pragma unroll
  for (int j = 0; j < NCH; ++j){
    int idx = j*256 + threadIdx.x;
    const bf16* p = g + (size_t)(idx >> SH)*gstr + (size_t)(idx & ((1<<SH)-1))*8;
    asm volatile("global_load_dwordx4 %0, %1, off sc0" : "=v"(tmp[j]) : "v"(p));
  }
  asm volatile("s_waitcnt vmcnt(0)" ::: "memory");
#pragma unroll
  for (int j = 0; j < NCH; ++j){
    int idx = j*256 + threadIdx.x;
    *(short8*)&lds[(idx >> SH)*lstr + (idx & ((1<<SH)-1))*8] = tmp[j];
  }
}
// Plain (L2-cached) staging for read-only inputs (x, W3)
template<int NCH, int SH>
__device__ __forceinline__ void stageP(bf16* lds, int lstr, const bf16* g, size_t gstr){
#pragma unroll
  for (int j = 0; j < NCH; ++j){
    int idx = j*256 + threadIdx.x;
    *(short8*)&lds[(idx >> SH)*lstr + (idx & ((1<<SH)-1))*8] =
        *(const short8*)(g + (size_t)(idx >> SH)*gstr + (size_t)(idx & ((1<<SH)-1))*8);
  }
}
__device__ __forceinline__ void stageW3(bf16* lds, const bf16* g){
#pragma unroll
  for (int j = 0; j < 16; ++j){
    int idx = j*256 + threadIdx.x;
    int r = idx >> 7, c = idx & 127;
    *(short8*)&lds[r*1032 + c*8] = *(const short8*)(g + (size_t)r*1024 + c*8);
  }
}

// LDS: slab 32x1032 @0 (66048) | W3s 32x1032 @66048 (66048) | scr 32x72 @132096
//      (4608) | t0s/dts/tcs @136704 (384) | dead/roleSh/fastSh @137088
__global__ __launch_bounds__(256, 1) void persist_k(
    const bf16* __restrict__ W1hb, const bf16* __restrict__ W2b,
    const bf16* __restrict__ W3b,  const bf16* __restrict__ Woutb,
    const bf16* __restrict__ Wc3,  const bf16* __restrict__ xbf,
    const float* __restrict__ b1,  const float* __restrict__ b2,
    const float* __restrict__ b3,  const float* __restrict__ bout,
    const float* __restrict__ bcb3,const float* __restrict__ w1t,
    const float* __restrict__ ts,
    bf16* wbuf, bf16* z1buf, bf16* z2buf,
    unsigned* cnts, unsigned* fmt, float* dout)
{
  extern __shared__ char smem[];
  bf16* slab = (bf16*)smem;
  bf16* W3s  = (bf16*)(smem + 66048);
  bf16* scr  = (bf16*)(smem + 132096);
  float* t0s = (float*)(smem + 136704);
  float* dts = t0s + 32;
  float* tcs = dts + 32;
  int* dead   = (int*)(smem + 137088);
  int* roleSh = dead + 1;
  int* fastSh = dead + 2;

  const int tid = threadIdx.x, lane = tid & 63, wv = tid >> 6;
  const int fr = lane & 15, quad = lane >> 4;
  const int bid = blockIdx.x;
  const int wm = wv & 1;              // row half
  const int wn2 = wv >> 1;            // 32-col slice (z phases)
  const int wn = wv >> 1;             // 16-col half (k/gates)

  if (tid == 0) *dead = 0;
  __syncthreads();

  // ============ team formation + probe verification ============
  unsigned* arr   = fmt;          // [256] xcd+1
  unsigned* arrc  = fmt + 256;
  unsigned* role  = fmt + 257;    // [256]
  unsigned* modeA = fmt + 513;    // [16]
  unsigned* done  = fmt + 529;
  unsigned* probe = fmt + 544;    // [256]
  unsigned* pcnt  = fmt + 800;    // [16]
  unsigned* pcnt2 = fmt + 816;    // [16]
  unsigned* chmode= fmt + 832;    // [16] nonzero -> force slow
  if (tid == 0){
    AST4(arr + bid, (unsigned)(xcc_id() + 1));
    __builtin_amdgcn_s_waitcnt(0);
    AADD(arrc);
    if (bid == 0){
      int it = 0;
      while (ALD4(arrc) < 256 && it < 60000000){ __builtin_amdgcn_s_sleep(2); ++it; }
      bool all = (ALD4(arrc) >= 256);
      int cnt[8]; int lst[8][64]; int lo[256]; int nlo = 0;
      for (int x = 0; x < 8; ++x) cnt[x] = 0;
      for (int b = 0; b < 256; ++b){
        int x = ((int)ALD4(arr + b) - 1) & 7;
        if (cnt[x] < 64) lst[x][cnt[x]++] = b; else lo[nlo++] = b;
      }
      int chain = 0;
      for (int x = 0; x < 8; ++x){
        int used = 0;
        while (cnt[x] - used >= 16 && chain < 16){
          for (int i = 0; i < 16; ++i) AST4(role + lst[x][used + i], (unsigned)(chain*16 + i));
          AST4(modeA + chain, all ? 1u : 0u);
          used += 16; ++chain;
        }
        while (used < cnt[x]) lo[nlo++] = lst[x][used++];
      }
      while (chain < 16){
        for (int i = 0; i < 16; ++i) AST4(role + lo[--nlo], (unsigned)(chain*16 + i));
        AST4(modeA + chain, 0u);
        ++chain;
      }
      __builtin_amdgcn_s_waitcnt(0);
      AST4(done, 1u);
    }
    int it = 0;
    while (ALD4(done) == 0 && it < 180000000){ __builtin_amdgcn_s_sleep(2); ++it; }
    int myrole = (int)ALD4(role + bid) & 255;
    int mb_ = myrole >> 4;
    int mode = (int)ALD4(modeA + mb_);
    // probe: write via fast store path, read via fast load path
    *(volatile unsigned*)(probe + myrole) = 0xC0DE0000u + (unsigned)myrole;
    __builtin_amdgcn_s_waitcnt(0);
    AADD(pcnt + mb_);
    it = 0;
    while (ALD4(pcnt + mb_) < 16 && it < 60000000){ __builtin_amdgcn_s_sleep(1); ++it; }
    int ok = (it < 60000000) ? 1 : 0;
    for (int i = 0; i < 16 && ok; ++i){
      unsigned pv;
      const unsigned* pp = probe + mb_*16 + i;
      asm volatile("global_load_dword %0, %1, off sc0" : "=v"(pv) : "v"(pp));
      asm volatile("s_waitcnt vmcnt(0)" ::: "memory");
      if (pv != 0xC0DE0000u + (unsigned)(mb_*16 + i)) ok = 0;
    }
    if (!ok || !mode) AADD(chmode + mb_);   // veto -> whole chain slow
    __builtin_amdgcn_s_waitcnt(0);
    AADD(pcnt2 + mb_);
    it = 0;
    while (ALD4(pcnt2 + mb_) < 16 && it < 60000000){ __builtin_amdgcn_s_sleep(1); ++it; }
    *roleSh = myrole;
    *fastSh = (ALD4(chmode + mb_) == 0) ? 1 : 0;
  }
  __syncthreads();
  const int mb = (*roleSh) >> 4, nb = (*roleSh) & 15, fast = *fastSh;
  const int gm0 = mb * 32;

  unsigned* cz1 = cnts + mb*128;
  unsigned* cz2 = cz1 + 32;
  unsigned* cw  = cz1 + 64;
  unsigned* cgt = cz1 + 96;

  // ============ one-time setup ============
  stageW3(W3s, W3b + (size_t)(32*nb)*1024);
  if (tid < 32){
    float t0 = ts[(gm0 + tid)*T_];
    t0s[tid] = t0; tcs[tid] = t0; dts[tid] = 0.f;
  }
  __syncthreads();

  float b1v[2], b2v[2], w1tv[2];
#pragma unroll
  for (int t = 0; t < 2; ++t){
    int col = 64*nb + 32*wn2 + 16*t + fr;
    b1v[t] = b1[col]; b2v[t] = b2[col]; w1tv[t] = w1t[col];
  }
  const float b3v = b3[32*nb + 16*wn + fr];
  float bcv[4];
#pragma unroll
  for (int g = 0; g < 4; ++g) bcv[g] = bcb3[nb*128 + g*32 + 16*wn + fr];
  const float bov = bout[16*(nb & 7) + fr];

  const bf16* w1p0 = W1hb + (size_t)(64*nb + 32*wn2      + fr)*512  + quad*8;
  const bf16* w1p1 = W1hb + (size_t)(64*nb + 32*wn2 + 16 + fr)*512  + quad*8;
  const bf16* w2p0 = W2b  + (size_t)(64*nb + 32*wn2      + fr)*1024 + quad*8;
  const bf16* w2p1 = W2b  + (size_t)(64*nb + 32*wn2 + 16 + fr)*1024 + quad*8;
  const bf16* wop  = Woutb + (size_t)(16*(nb & 7) + fr)*512 + quad*8;
  const bf16* wcp[4];
#pragma unroll
  for (int g = 0; g < 4; ++g)
    wcp[g] = Wc3 + (size_t)(nb*128 + g*32 + 16*wn + fr)*1024 + quad*8;

  float hreg[4] = {0,0,0,0}, kacc[4] = {0,0,0,0};
  unsigned tz1 = 16, tz2 = 16, tw = 16, tg = 16;
  const int rp64_r = tid >> 3, rp64_c = tid & 7;     // 32 x 64-col repack
  const int rp32_r = tid >> 2, rp32_c = tid & 3;     // 32 x 32-col repack

  for (int s = 0; s < T_; ++s){
    for (int sub = 0; sub < 4; ++sub){
      for (int e = 1; e <= 4; ++e){
        // ===== z1 = swish(w @ W1^T + t*w1t + b1), M32 N64 K512 =====
        wait_ge(cw, tw, dead);
        if (fast) stageF<8,6>(slab, 520, wbuf + (size_t)gm0*512, 512);
        else      stageC<16,7>(slab, 520, wbuf + (size_t)gm0*512, 512);
        __syncthreads();
        {
          f32x4 a0 = {0,0,0,0}, a1 = {0,0,0,0};
#pragma unroll 4
          for (int k = 0; k < 16; ++k){
            short8 x = *(const short8*)&slab[(wm*16 + fr)*520 + k*32 + quad*8];
            a0 = MFMA16(x, *(const short8*)(w1p0 + k*32), a0);
            a1 = MFMA16(x, *(const short8*)(w1p1 + k*32), a1);
          }
#pragma unroll
          for (int j = 0; j < 4; ++j){
            int r = wm*16 + quad*4 + j;
            float v0 = a0[j] + b1v[0] + tcs[r]*w1tv[0];
            float v1 = a1[j] + b1v[1] + tcs[r]*w1tv[1];
            scr[r*72 + 32*wn2      + fr] = __float2bfloat16(v0*sigm(v0));
            scr[r*72 + 32*wn2 + 16 + fr] = __float2bfloat16(v1*sigm(v1));
          }
          __syncthreads();
          {
            u64* dst = (u64*)(z1buf + (size_t)(gm0 + rp64_r)*1024 + 64*nb + rp64_c*8);
            const u64* src = (const u64*)&scr[rp64_r*72 + rp64_c*8];
            if (fast){ dst[0] = src[0]; dst[1] = src[1]; }
            else     { AST8(dst, src[0]); AST8(dst + 1, src[1]); }
          }
          publish(cz1);
        }
        // ===== z2 = swish(z1 @ W2^T + b2), M32 N64 K1024 =====
        wait_ge(cz1, tz1, dead); tz1 += 16;
        if (fast) stageF<16,7>(slab, 1032, z1buf + (size_t)gm0*1024, 1024);
        else      stageC<32,8>(slab, 1032, z1buf + (size_t)gm0*1024, 1024);
        __syncthreads();
        {
          f32x4 a0 = {0,0,0,0}, a1 = {0,0,0,0};
#pragma unroll 4
          for (int k = 0; k < 32; ++k){
            short8 x = *(const short8*)&slab[(wm*16 + fr)*1032 + k*32 + quad*8];
            a0 = MFMA16(x, *(const short8*)(w2p0 + k*32), a0);
            a1 = MFMA16(x, *(const short8*)(w2p1 + k*32), a1);
          }
#pragma unroll
          for (int j = 0; j < 4; ++j){
            int r = wm*16 + quad*4 + j;
            float v0 = a0[j] + b2v[0], v1 = a1[j] + b2v[1];
            scr[r*72 + 32*wn2      + fr] = __float2bfloat16(v0*sigm(v0));
            scr[r*72 + 32*wn2 + 16 + fr] = __float2bfloat16(v1*sigm(v1));
          }
          __syncthreads();
          {
            u64* dst = (u64*)(z2buf + (size_t)(gm0 + rp64_r)*1024 + 64*nb + rp64_c*8);
            const u64* src = (const u64*)&scr[rp64_r*72 + rp64_c*8];
            if (fast){ dst[0] = src[0]; dst[1] = src[1]; }
            else     { AST8(dst, src[0]); AST8(dst + 1, src[1]); }
          }
          publish(cz2);
        }
        // ===== k = z2 @ W3^T + b3 ; RK4 in registers, M32 N32 K1024 =====
        wait_ge(cz2, tz2, dead); tz2 += 16;
        if (fast) stageF<16,7>(slab, 1032, z2buf + (size_t)gm0*1024, 1024);
        else      stageC<32,8>(slab, 1032, z2buf + (size_t)gm0*1024, 1024);
        __syncthreads();
        {
          f32x4 ak = {0,0,0,0};
#pragma unroll 8
          for (int k = 0; k < 32; ++k){
            short8 x = *(const short8*)&slab[(wm*16 + fr)*1032 + k*32 + quad*8];
            short8 b = *(const short8*)&W3s[(wn*16 + fr)*1032 + k*32 + quad*8];
            ak = MFMA16(x, b, ak);
          }
#pragma unroll
          for (int j = 0; j < 4; ++j){
            int row = wm*16 + quad*4 + j;
            float v = ak[j] + b3v;
            float dtv = dts[row];
            float ka = (e == 1) ? v : kacc[j] + ((e == 4) ? 1.f : 2.f)*v;
            float wn_;
            if (e < 4){ kacc[j] = ka; wn_ = hreg[j] + ((e == 3) ? 1.f : 0.5f)*dtv*v; }
            else      { hreg[j] = hreg[j] + dtv*(1.f/6.f)*ka; wn_ = hreg[j]; }
            scr[row*72 + wn*16 + fr] = __float2bfloat16(wn_);
          }
          __syncthreads();
          if (tid < 128){
            u64* dst = (u64*)(wbuf + (size_t)(gm0 + rp32_r)*512 + 32*nb + rp32_c*8);
            const u64* src = (const u64*)&scr[rp32_r*72 + rp32_c*8];
            if (fast){ dst[0] = src[0]; dst[1] = src[1]; }
            else     { AST8(dst, src[0]); AST8(dst + 1, src[1]); }
          }
          if (tid < 32){
            float ce = (e <= 2) ? ((float)sub + 0.5f) : ((float)sub + 1.f);
            tcs[tid] = t0s[tid] + dts[tid]*ce;
          }
          publish(cw); tw += 16;
        }
      }
    }
    // ===== gates: [w|x_s] @ Wc3^T (groups r|z|hn|in x 32 cols), K=1024 =====
    wait_ge(cw, tw, dead);
    if (fast) stageF<8,6>(slab, 1032, wbuf + (size_t)gm0*512, 512);
    else      stageC<16,7>(slab, 1032, wbuf + (size_t)gm0*512, 512);
    stageP<8,6>(slab + 512, 1032, xbf + ((size_t)gm0*T_ + s)*512, (size_t)T_*512);
    __syncthreads();
    publish(cgt);   // old w consumed (staged); overwrite only after all 16
    {
      f32x4 ag[4] = {{0,0,0,0},{0,0,0,0},{0,0,0,0},{0,0,0,0}};
#pragma unroll 4
      for (int k = 0; k < 32; ++k){
        short8 x = *(const short8*)&slab[(wm*16 + fr)*1032 + k*32 + quad*8];
#pragma unroll
        for (int g = 0; g < 4; ++g)
          ag[g] = MFMA16(x, *(const short8*)(wcp[g] + k*32), ag[g]);
      }
      wait_ge(cgt, tg, dead); tg += 16;
#pragma unroll
      for (int j = 0; j < 4; ++j){
        int row = wm*16 + quad*4 + j;
        float r_ = sigm(ag[0][j] + bcv[0]);
        float z_ = sigm(ag[1][j] + bcv[1]);
        float hn = ag[2][j] + bcv[2];
        float in = ag[3][j] + bcv[3];
        float n_ = tanhf(in + r_*hn);
        hreg[j] = (1.f - z_)*n_ + z_*hreg[j];
        scr[row*72 + wn*16 + fr] = __float2bfloat16(hreg[j]);
      }
      __syncthreads();
      if (tid < 128){
        u64* dst = (u64*)(wbuf + (size_t)(gm0 + rp32_r)*512 + 32*nb + rp32_c*8);
        const u64* src = (const u64*)&scr[rp32_r*72 + rp32_c*8];
        if (fast){ dst[0] = src[0]; dst[1] = src[1]; }
        else     { AST8(dst, src[0]); AST8(dst + 1, src[1]); }
      }
      if (tid < 32){
        float t0n = ts[(gm0 + tid)*T_ + s];
        float t1  = (s < T_-1) ? ts[(gm0 + tid)*T_ + s + 1] : t0n;
        t0s[tid] = t0n; tcs[tid] = t0n; dts[tid] = (t1 - t0n)*0.25f;
      }
      publish(cw); tw += 16;
    }
  }
  // ===== final: out = h @ Wout^T + bout ; h ; c = 0 =====
  wait_ge(cw, tw, dead);
  if (fast) stageF<8,6>(slab, 520, wbuf + (size_t)gm0*512, 512);
  else      stageC<16,7>(slab, 520, wbuf + (size_t)gm0*512, 512);
  __syncthreads();
  if (nb < 8 && wv < 2){
    f32x4 ao = {0,0,0,0};
#pragma unroll 4
    for (int k = 0; k < 16; ++k){
      short8 x = *(const short8*)&slab[(wv*16 + fr)*520 + k*32 + quad*8];
      ao = MFMA16(x, *(const short8*)(wop + k*32), ao);
    }
#pragma unroll
    for (int j = 0; j < 4; ++j)
      dout[(size_t)(gm0 + wv*16 + quad*4 + j)*128 + 16*nb + fr] = ao[j] + bov;
  }
#pragma unroll
  for (int j = 0; j < 4; ++j){
    int row = gm0 + wm*16 + quad*4 + j, col = 32*nb + 16*wn + fr;
    dout[(size_t)B_*128 + (size_t)row*512 + col] = hreg[j];
    dout[(size_t)B_*128 + (size_t)B_*512 + (size_t)row*512 + col] = 0.f;
  }
}

// ---- prolog kernels ----
__global__ void conv_k(const float* __restrict__ in, bf16* __restrict__ out,
                       int rows, int kin, int kout)
{
  int idx = blockIdx.x*256 + threadIdx.x;
  if (idx >= rows*kout) return;
  int r = idx / kout, k = idx - r*kout;
  out[idx] = __float2bfloat16(k < kin ? in[(size_t)r*kin + k] : 0.f);
}

__global__ void w1t_k(const float* __restrict__ W1, float* __restrict__ w1t)
{
  int i = blockIdx.x*256 + threadIdx.x;
  if (i < 1024) w1t[i] = W1[(size_t)i*513 + 512];
}

// Wc3 row R = n16*128 + g*32 + c; hidden col hc = n16*32 + c.
__global__ void wc3_k(const float* __restrict__ Wih, const float* __restrict__ Whh,
                      const float* __restrict__ bih, const float* __restrict__ bhh,
                      bf16* __restrict__ Wc3, float* __restrict__ bcb3)
{
  int idx = blockIdx.x*256 + threadIdx.x;
  if (idx >= 2048*1024) return;
  int R = idx >> 10, k = idx & 1023;
  int n16 = R >> 7, g = (R >> 5) & 3, c = R & 31;
  int hc = n16*32 + c;
  float v;
  if      (g == 0) v = (k < 512) ? Whh[(size_t)hc*512 + k]        : Wih[(size_t)hc*512 + k - 512];
  else if (g == 1) v = (k < 512) ? Whh[(size_t)(512+hc)*512 + k]  : Wih[(size_t)(512+hc)*512 + k - 512];
  else if (g == 2) v = (k < 512) ? Whh[(size_t)(1024+hc)*512 + k] : 0.f;
  else             v = (k < 512) ? 0.f                             : Wih[(size_t)(1024+hc)*512 + k - 512];
  Wc3[idx] = __float2bfloat16(v);
  if (k == 0){
    if      (g == 0) bcb3[R] = bih[hc] + bhh[hc];
    else if (g == 1) bcb3[R] = bih[512 + hc] + bhh[512 + hc];
    else if (g == 2) bcb3[R] = bhh[1024 + hc];
    else             bcb3[R] = bih[1024 + hc];
  }
}

__global__ void init_k(bf16* __restrict__ wbuf, unsigned* __restrict__ cnts,
                       unsigned* __restrict__ fmt)
{
  int idx = blockIdx.x*256 + threadIdx.x;
  if (idx < B_*H_) wbuf[idx] = __float2bfloat16(0.f);
  if (idx < 16*128) cnts[idx] = ((idx & 127) == 64) ? 16u : 0u;  // cw pre-armed
  if (idx < 1024) fmt[idx] = 0u;
}

extern "C" void kernel_launch(void* const* d_in, const int* in_sizes, int n_in,
                              void* d_out, int out_size, void* d_ws, size_t ws_size,
                              hipStream_t stream)
{
  const float* x    = (const float*)d_in[0];
  const float* ts   = (const float*)d_in[1];
  const float* Wih  = (const float*)d_in[2];
  const float* Whh  = (const float*)d_in[3];
  const float* bih  = (const float*)d_in[4];
  const float* bhh  = (const float*)d_in[5];
  const float* Wout = (const float*)d_in[6];
  const float* bout = (const float*)d_in[7];
  const float* W1   = (const float*)d_in[8];
  const float* b1   = (const float*)d_in[9];
  const float* W2   = (const float*)d_in[10];
  const float* b2   = (const float*)d_in[11];
  const float* W3   = (const float*)d_in[12];
  const float* b3   = (const float*)d_in[13];

  char* ws = (char*)d_ws;
  size_t off = 0;
  auto alloc = [&](size_t n){ void* p = ws + off; off += (n + 255) & ~(size_t)255; return p; };

  bf16* xbf   = (bf16*)alloc((size_t)B_*T_*D_*2);
  bf16* W1hb  = (bf16*)alloc((size_t)1024*512*2);
  bf16* W2b   = (bf16*)alloc((size_t)1024*1024*2);
  bf16* W3b   = (bf16*)alloc((size_t)512*1024*2);
  bf16* Woutb = (bf16*)alloc((size_t)128*512*2);
  bf16* Wc3   = (bf16*)alloc((size_t)2048*1024*2);
  float* bcb3 = (float*)alloc((size_t)2048*4);
  float* w1t  = (float*)alloc((size_t)1024*4);
  bf16* wbuf  = (bf16*)alloc((size_t)B_*H_*2);
  bf16* z1buf = (bf16*)alloc((size_t)B_*1024*2);
  bf16* z2buf = (bf16*)alloc((size_t)B_*1024*2);
  unsigned* cnts = (unsigned*)alloc((size_t)16*128*4);
  unsigned* fmt  = (unsigned*)alloc((size_t)1024*4);

  auto conv = [&](const float* in, bf16* out, int rows, int kin, int kout){
    int n = rows*kout;
    conv_k<<<(n + 255)/256, 256, 0, stream>>>(in, out, rows, kin, kout);
  };
  conv(x, xbf, B_*T_, D_, D_);
  conv(W1, W1hb, 1024, 513, 512);   // col 512 via w1t rank-1 term
  conv(W2, W2b, 1024, 1024, 1024);
  conv(W3, W3b, 512, 1024, 1024);
  conv(Wout, Woutb, 128, 512, 512);
  w1t_k<<<4, 256, 0, stream>>>(W1, w1t);
  wc3_k<<<(2048*1024)/256, 256, 0, stream>>>(Wih, Whh, bih, bhh, Wc3, bcb3);
  init_k<<<(B_*H_ + 255)/256, 256, 0, stream>>>(wbuf, cnts, fmt);

  (void)hipFuncSetAttribute((const void*)persist_k,
                            hipFuncAttributeMaxDynamicSharedMemorySize, 137216);
  persist_k<<<256, 256, 137216, stream>>>(
      W1hb, W2b, W3b, Woutb, Wc3, xbf,
      b1, b2, b3, bout, bcb3, w1t, ts,
      wbuf, z1buf, z2buf, cnts, fmt, (float*)d_out);
}